// Round 13
// baseline (585.990 us; speedup 1.0000x reference)
//
#include <hip/hip_runtime.h>
#include <math.h>

// SimpleGNN: out = softplus(A(relu(A(relu(A(x W1)+b1) W2)+b2) Wout)+bout)
// using spmm(x) @ W == spmm(x @ W) to make the last spmm D=1.
// CSR edges as packed (col,val) int2; XCD-affine scatter (blockIdx&7 = row range),
// all 3 edge streams nt-loaded. N x 128 intermediates bf16 (fp32 accumulation).
// GEMMs: v_mfma_f32_16x16x32_bf16. SpMM: one wave/row, padded 8-wide gather
// pipeline (clamped index + masked val -> no serial tail).

typedef unsigned int u32;
typedef unsigned short u16;
typedef __attribute__((ext_vector_type(8))) short bf16x8;
typedef __attribute__((ext_vector_type(4))) float f32x4;

__device__ inline float bf2f(u32 lo16){ return __uint_as_float(lo16 << 16); }
__device__ inline u32 f2bf(float f){            // round-to-nearest-even
  u32 t = __float_as_uint(f);
  return (t + 0x7FFFu + ((t >> 16) & 1u)) >> 16;
}

// ---------------- CSR build ----------------
__global__ void k_hist(const int* __restrict__ row, int* __restrict__ cnt, int E){
  int e = blockIdx.x*256 + threadIdx.x;
  if(e < E) atomicAdd(&cnt[__builtin_nontemporal_load(&row[e])], 1);
}

__global__ void k_scan1(const int* __restrict__ cnt, int* __restrict__ scanned,
                        int* __restrict__ sums, int n){
  __shared__ int tmp[1024];
  int i = blockIdx.x*1024 + threadIdx.x;
  int v = (i<n)? cnt[i] : 0;
  tmp[threadIdx.x] = v;
  __syncthreads();
  for(int off=1; off<1024; off<<=1){
    int t = (threadIdx.x>=off)? tmp[threadIdx.x-off] : 0;
    __syncthreads();
    tmp[threadIdx.x] += t;
    __syncthreads();
  }
  if(i<n) scanned[i] = tmp[threadIdx.x] - v;
  if(threadIdx.x==1023) sums[blockIdx.x] = tmp[1023];
}

__global__ void k_scan2(int* sums, int ntiles){
  if(threadIdx.x==0 && blockIdx.x==0){
    int acc=0;
    for(int i=0;i<ntiles;i++){ int v=sums[i]; sums[i]=acc; acc+=v; }
  }
}

__global__ void k_scan3(const int* __restrict__ scanned, const int* __restrict__ sums,
                        int* __restrict__ row_ptr, int* __restrict__ offs, int n, int E){
  int i = blockIdx.x*256 + threadIdx.x;
  if(i<n){ int ex = scanned[i] + sums[i>>10]; row_ptr[i]=ex; offs[i]=ex; }
  else if(i==n){ row_ptr[n]=E; }
}

// XCD-affine scatter
__global__ __launch_bounds__(256) void k_scatter(const int* __restrict__ row,
                          const int* __restrict__ col,
                          const float* __restrict__ val, int* __restrict__ offs,
                          int2* __restrict__ pairs, int E, int N){
  const int r   = blockIdx.x & 7;
  const int sb  = blockIdx.x >> 3;
  const int nsb = gridDim.x >> 3;
  const int rpr = (N + 7) >> 3;
  const int lo  = r * rpr;
  const int hi  = min(lo + rpr, N);
  const int stride = nsb * 256;
  for(int e = sb*256 + threadIdx.x; e < E; e += stride){
    int rw = __builtin_nontemporal_load(&row[e]);
    if(rw >= lo && rw < hi){
      int   c = __builtin_nontemporal_load(&col[e]);
      float v = __builtin_nontemporal_load(&val[e]);
      int p = atomicAdd(&offs[rw], 1);
      pairs[p] = make_int2(c, __float_as_int(v));
    }
  }
}

// ---------------- W pre-transpose + cvt ----------------
__global__ void k_cvtW(const float* __restrict__ W, u16* __restrict__ Wt){
  int t = blockIdx.x*256 + threadIdx.x;
  int nn = t >> 7, k = t & 127;
  Wt[nn*128 + k] = (u16)f2bf(W[k*128 + nn]);
}

// ---------------- MFMA GEMM ----------------
template<bool A_BF16>
__global__ __launch_bounds__(256) void k_gemm(const void* __restrict__ Xv,
                                              const u16* __restrict__ Wt,
                                              u16* __restrict__ Y, int n){
  __shared__ u16 As[128*128];
  __shared__ u16 Bs[128*128];
  const int t = threadIdx.x;
  const int row0 = blockIdx.x * 128;

  {
    int r = t>>1, q = t&1;
    const uint4* src = (const uint4*)(Wt + r*128 + q*64);
    #pragma unroll
    for(int i=0;i<8;i++){
      uint4 v = src[i];
      int c = q*8 + i;
      *(uint4*)&Bs[r*128 + ((c ^ (r&15))<<3)] = v;
    }
  }
  {
    int r = t>>1, q = t&1;
    int gr = row0 + r;
    if(A_BF16){
      const uint4* src = (const uint4*)((const u16*)Xv + (size_t)gr*128 + q*64);
      uint4 z = make_uint4(0,0,0,0);
      #pragma unroll
      for(int i=0;i<8;i++){
        uint4 v = (gr<n)? src[i] : z;
        int c = q*8 + i;
        *(uint4*)&As[r*128 + ((c ^ (r&15))<<3)] = v;
      }
    }else{
      const float4* src = (const float4*)((const float*)Xv + (size_t)gr*128 + q*64);
      float4 z4 = make_float4(0,0,0,0);
      #pragma unroll
      for(int i=0;i<8;i++){
        float4 a = (gr<n)? src[2*i]   : z4;
        float4 b = (gr<n)? src[2*i+1] : z4;
        uint4 v = make_uint4(f2bf(a.x)|(f2bf(a.y)<<16), f2bf(a.z)|(f2bf(a.w)<<16),
                             f2bf(b.x)|(f2bf(b.y)<<16), f2bf(b.z)|(f2bf(b.w)<<16));
        int c = q*8 + i;
        *(uint4*)&As[r*128 + ((c ^ (r&15))<<3)] = v;
      }
    }
  }
  __syncthreads();

  const int w  = t>>6, l = t&63;
  const int lr = l & 15;
  const int kg = l >> 4;
  f32x4 acc[2][8];
  #pragma unroll
  for(int mi=0;mi<2;mi++)
    #pragma unroll
    for(int ni=0;ni<8;ni++) acc[mi][ni] = (f32x4){0.f,0.f,0.f,0.f};

  #pragma unroll
  for(int kt=0; kt<4; kt++){
    int c = kt*4 + kg;
    bf16x8 a0 = *(const bf16x8*)&As[(w*32 + lr)*128      + ((c ^ lr)<<3)];
    bf16x8 a1 = *(const bf16x8*)&As[(w*32 + 16 + lr)*128 + ((c ^ lr)<<3)];
    #pragma unroll
    for(int ni=0; ni<8; ni++){
      bf16x8 b = *(const bf16x8*)&Bs[(ni*16 + lr)*128 + ((c ^ lr)<<3)];
      acc[0][ni] = __builtin_amdgcn_mfma_f32_16x16x32_bf16(a0, b, acc[0][ni], 0,0,0);
      acc[1][ni] = __builtin_amdgcn_mfma_f32_16x16x32_bf16(a1, b, acc[1][ni], 0,0,0);
    }
  }

  #pragma unroll
  for(int mi=0;mi<2;mi++){
    #pragma unroll
    for(int r=0;r<4;r++){
      int grow = row0 + w*32 + mi*16 + kg*4 + r;
      if(grow < n){
        #pragma unroll
        for(int ni=0;ni<8;ni++){
          Y[(size_t)grow*128 + ni*16 + lr] = (u16)f2bf(acc[mi][ni][r]);
        }
      }
    }
  }
}

// ---------------- SpMM (D=128 bf16) + bias + relu -> bf16 ----------------
// one wave per row; padded 8-wide: all gathers issued every iter, pads clamped
// to e-1 (L1-hot same line) with val forced to 0.
__global__ __launch_bounds__(256) void k_spmm_relu(const int* __restrict__ row_ptr,
                                                   const int2* __restrict__ pairs,
                                                   const u16* __restrict__ y,
                                                   const float* __restrict__ bias,
                                                   u16* __restrict__ h, int n){
  int wid  = (int)((blockIdx.x*(size_t)blockDim.x + threadIdx.x) >> 6);
  int lane = threadIdx.x & 63;
  if(wid >= n) return;
  int s = row_ptr[wid], e = row_ptr[wid+1];
  float ax[8] = {0,0,0,0,0,0,0,0};
  float ay[8] = {0,0,0,0,0,0,0,0};
  for(int i = s; i < e; i += 8){
    u32 w[8]; float v[8];
    #pragma unroll
    for(int u=0;u<8;u++){
      int  q  = i + u;
      bool ok = q < e;
      int2 p  = pairs[ok ? q : e-1];
      v[u] = ok ? __int_as_float(p.y) : 0.f;
      w[u] = ((const u32*)(y + (size_t)p.x*128))[lane];
    }
    #pragma unroll
    for(int u=0;u<8;u++){
      ax[u] = fmaf(v[u], bf2f(w[u]&0xffff), ax[u]);
      ay[u] = fmaf(v[u], bf2f(w[u]>>16),   ay[u]);
    }
  }
  float accx = ((ax[0]+ax[1])+(ax[2]+ax[3])) + ((ax[4]+ax[5])+(ax[6]+ax[7]));
  float accy = ((ay[0]+ay[1])+(ay[2]+ay[3])) + ((ay[4]+ay[5])+(ay[6]+ay[7]));
  float2 b = ((const float2*)bias)[lane];
  accx = fmaxf(accx + b.x, 0.f);
  accy = fmaxf(accy + b.y, 0.f);
  ((u32*)(h + (size_t)wid*128))[lane] = f2bf(accx) | (f2bf(accy)<<16);
}

// ---------------- SpMM(bf16) + bias + relu + head dot, fused -> z fp32 ----------------
__global__ __launch_bounds__(256) void k_spmm_head(const int* __restrict__ row_ptr,
                                                   const int2* __restrict__ pairs,
                                                   const u16* __restrict__ y,
                                                   const float* __restrict__ bias,
                                                   const float* __restrict__ Wout,
                                                   float* __restrict__ z, int n){
  int wid  = (int)((blockIdx.x*(size_t)blockDim.x + threadIdx.x) >> 6);
  int lane = threadIdx.x & 63;
  if(wid >= n) return;
  int s = row_ptr[wid], e = row_ptr[wid+1];
  float ax[8] = {0,0,0,0,0,0,0,0};
  float ay[8] = {0,0,0,0,0,0,0,0};
  for(int i = s; i < e; i += 8){
    u32 w[8]; float v[8];
    #pragma unroll
    for(int u=0;u<8;u++){
      int  q  = i + u;
      bool ok = q < e;
      int2 p  = pairs[ok ? q : e-1];
      v[u] = ok ? __int_as_float(p.y) : 0.f;
      w[u] = ((const u32*)(y + (size_t)p.x*128))[lane];
    }
    #pragma unroll
    for(int u=0;u<8;u++){
      ax[u] = fmaf(v[u], bf2f(w[u]&0xffff), ax[u]);
      ay[u] = fmaf(v[u], bf2f(w[u]>>16),   ay[u]);
    }
  }
  float accx = ((ax[0]+ax[1])+(ax[2]+ax[3])) + ((ax[4]+ax[5])+(ax[6]+ax[7]));
  float accy = ((ay[0]+ay[1])+(ay[2]+ay[3])) + ((ay[4]+ay[5])+(ay[6]+ay[7]));
  float2 b  = ((const float2*)bias)[lane];
  float2 wv = ((const float2*)Wout)[lane];
  float hx = fmaxf(accx + b.x, 0.f);
  float hy = fmaxf(accy + b.y, 0.f);
  float p = hx*wv.x + hy*wv.y;
  #pragma unroll
  for(int off=32; off; off>>=1) p += __shfl_down(p, off);
  if(lane==0) z[wid] = p;
}

// ---------------- final: out[r] = softplus(sum val*z[col] + bout) ----------------
__global__ void k_spmm1_softplus(const int* __restrict__ row_ptr,
                                 const int2* __restrict__ pairs,
                                 const float* __restrict__ z,
                                 const float* __restrict__ bout,
                                 float* __restrict__ out, int n){
  int r = blockIdx.x*256 + threadIdx.x;
  if(r >= n) return;
  int s = row_ptr[r], e = row_ptr[r+1];
  float a0=0.f, a1=0.f, a2=0.f, a3=0.f;
  int i = s;
  for(; i+4 <= e; i += 4){
    int2 p0 = pairs[i],   p1 = pairs[i+1], p2 = pairs[i+2], p3 = pairs[i+3];
    a0 = fmaf(__int_as_float(p0.y), z[p0.x], a0);
    a1 = fmaf(__int_as_float(p1.y), z[p1.x], a1);
    a2 = fmaf(__int_as_float(p2.y), z[p2.x], a2);
    a3 = fmaf(__int_as_float(p3.y), z[p3.x], a3);
  }
  for(; i < e; i++){
    int2 p = pairs[i];
    a0 = fmaf(__int_as_float(p.y), z[p.x], a0);
  }
  float x = (a0+a1)+(a2+a3) + bout[0];
  out[r] = fmaxf(x, 0.f) + log1pf(expf(-fabsf(x)));
}

extern "C" void kernel_launch(void* const* d_in, const int* in_sizes, int n_in,
                              void* d_out, int out_size, void* d_ws, size_t ws_size,
                              hipStream_t stream){
  const float* x    = (const float*)d_in[0];
  const int*   erow = (const int*)d_in[1];
  const int*   ecol = (const int*)d_in[2];
  const float* eval = (const float*)d_in[3];
  const float* W1   = (const float*)d_in[4];
  const float* b1   = (const float*)d_in[5];
  const float* W2   = (const float*)d_in[6];
  const float* b2   = (const float*)d_in[7];
  const float* Wout = (const float*)d_in[8];
  const float* bout = (const float*)d_in[9];
  float* out = (float*)d_out;

  const int N = in_sizes[0] / 128;   // 100000
  const int E = in_sizes[1];         // 1600000

  char* p = (char*)d_ws;
  auto alloc = [&](size_t bytes)->char*{
    char* r = p; p += (bytes + 255) & ~(size_t)255; return r;
  };
  int*   cnt     = (int*)  alloc((size_t)N*4);
  int*   row_ptr = (int*)  alloc((size_t)(N+1)*4);
  int*   offs    = (int*)  alloc((size_t)N*4);
  int*   scanned = (int*)  alloc((size_t)N*4);
  int*   sums    = (int*)  alloc(4096);
  int2*  pairs   = (int2*) alloc((size_t)E*8);
  u16*   ybuf    = (u16*)  alloc((size_t)N*128*2);
  u16*   hbuf    = (u16*)  alloc((size_t)N*128*2);
  float* z       = (float*)alloc((size_t)N*4);
  u16*   Wt1     = (u16*)  alloc(128*128*2);
  u16*   Wt2     = (u16*)  alloc(128*128*2);

  // CSR build
  hipMemsetAsync(cnt, 0, (size_t)N*4, stream);
  k_hist<<<(E+255)/256, 256, 0, stream>>>(erow, cnt, E);
  int ntiles = (N+1023)/1024;
  k_scan1<<<ntiles, 1024, 0, stream>>>(cnt, scanned, sums, N);
  k_scan2<<<1, 64, 0, stream>>>(sums, ntiles);
  k_scan3<<<(N+1+255)/256, 256, 0, stream>>>(scanned, sums, row_ptr, offs, N, E);
  k_scatter<<<1024, 256, 0, stream>>>(erow, ecol, eval, offs, pairs, E, N);

  // W pre-transpose/convert
  k_cvtW<<<64, 256, 0, stream>>>(W1, Wt1);
  k_cvtW<<<64, 256, 0, stream>>>(W2, Wt2);

  // layer 1: y = x@W1 (bf16 MFMA) ; h = relu(A y + b1) (bf16)
  k_gemm<false><<<(N+127)/128, 256, 0, stream>>>(x, Wt1, ybuf, N);
  k_spmm_relu<<<(N+3)/4, 256, 0, stream>>>(row_ptr, pairs, ybuf, b1, hbuf, N);
  // layer 2: y = h@W2 (bf16 MFMA) ; z = relu(A y + b2) . Wout
  k_gemm<true><<<(N+127)/128, 256, 0, stream>>>(hbuf, Wt2, ybuf, N);
  k_spmm_head<<<(N+3)/4, 256, 0, stream>>>(row_ptr, pairs, ybuf, b2, Wout, z, N);
  // out = softplus(A z + bout)
  k_spmm1_softplus<<<(N+255)/256, 256, 0, stream>>>(row_ptr, pairs, z, bout, out, N);
}

// Round 14
// 468.363 us; speedup vs baseline: 1.2511x; 1.2511x over previous
//
#include <hip/hip_runtime.h>
#include <math.h>

// SimpleGNN: out = softplus(A(relu(A(relu(A(x W1)+b1) W2)+b2) Wout)+bout)
// using spmm(x) @ W == spmm(x @ W) to make the last spmm D=1.
// CSR edges as packed (col,val) int2; XCD-affine scatter (blockIdx&7 = row range),
// all 3 edge streams nt-loaded. N x 128 intermediates bf16 (fp32 accumulation).
// GEMMs: v_mfma_f32_16x16x32_bf16. SpMM: quarter-wave per row (16 lanes x 16B),
// 8-deep gather unroll (32 edges in flight per wave), single padded epilogue.

typedef unsigned int u32;
typedef unsigned short u16;
typedef __attribute__((ext_vector_type(8))) short bf16x8;
typedef __attribute__((ext_vector_type(4))) float f32x4;

__device__ inline float bf2f(u32 lo16){ return __uint_as_float(lo16 << 16); }
__device__ inline u32 f2bf(float f){            // round-to-nearest-even
  u32 t = __float_as_uint(f);
  return (t + 0x7FFFu + ((t >> 16) & 1u)) >> 16;
}

// ---------------- CSR build ----------------
__global__ void k_hist(const int* __restrict__ row, int* __restrict__ cnt, int E){
  int e = blockIdx.x*256 + threadIdx.x;
  if(e < E) atomicAdd(&cnt[__builtin_nontemporal_load(&row[e])], 1);
}

__global__ void k_scan1(const int* __restrict__ cnt, int* __restrict__ scanned,
                        int* __restrict__ sums, int n){
  __shared__ int tmp[1024];
  int i = blockIdx.x*1024 + threadIdx.x;
  int v = (i<n)? cnt[i] : 0;
  tmp[threadIdx.x] = v;
  __syncthreads();
  for(int off=1; off<1024; off<<=1){
    int t = (threadIdx.x>=off)? tmp[threadIdx.x-off] : 0;
    __syncthreads();
    tmp[threadIdx.x] += t;
    __syncthreads();
  }
  if(i<n) scanned[i] = tmp[threadIdx.x] - v;
  if(threadIdx.x==1023) sums[blockIdx.x] = tmp[1023];
}

__global__ void k_scan2(int* sums, int ntiles){
  if(threadIdx.x==0 && blockIdx.x==0){
    int acc=0;
    for(int i=0;i<ntiles;i++){ int v=sums[i]; sums[i]=acc; acc+=v; }
  }
}

__global__ void k_scan3(const int* __restrict__ scanned, const int* __restrict__ sums,
                        int* __restrict__ row_ptr, int* __restrict__ offs, int n, int E){
  int i = blockIdx.x*256 + threadIdx.x;
  if(i<n){ int ex = scanned[i] + sums[i>>10]; row_ptr[i]=ex; offs[i]=ex; }
  else if(i==n){ row_ptr[n]=E; }
}

// XCD-affine scatter
__global__ __launch_bounds__(256) void k_scatter(const int* __restrict__ row,
                          const int* __restrict__ col,
                          const float* __restrict__ val, int* __restrict__ offs,
                          int2* __restrict__ pairs, int E, int N){
  const int r   = blockIdx.x & 7;
  const int sb  = blockIdx.x >> 3;
  const int nsb = gridDim.x >> 3;
  const int rpr = (N + 7) >> 3;
  const int lo  = r * rpr;
  const int hi  = min(lo + rpr, N);
  const int stride = nsb * 256;
  for(int e = sb*256 + threadIdx.x; e < E; e += stride){
    int rw = __builtin_nontemporal_load(&row[e]);
    if(rw >= lo && rw < hi){
      int   c = __builtin_nontemporal_load(&col[e]);
      float v = __builtin_nontemporal_load(&val[e]);
      int p = atomicAdd(&offs[rw], 1);
      pairs[p] = make_int2(c, __float_as_int(v));
    }
  }
}

// ---------------- W pre-transpose + cvt ----------------
__global__ void k_cvtW(const float* __restrict__ W, u16* __restrict__ Wt){
  int t = blockIdx.x*256 + threadIdx.x;
  int nn = t >> 7, k = t & 127;
  Wt[nn*128 + k] = (u16)f2bf(W[k*128 + nn]);
}

// ---------------- MFMA GEMM ----------------
template<bool A_BF16>
__global__ __launch_bounds__(256) void k_gemm(const void* __restrict__ Xv,
                                              const u16* __restrict__ Wt,
                                              u16* __restrict__ Y, int n){
  __shared__ u16 As[128*128];
  __shared__ u16 Bs[128*128];
  const int t = threadIdx.x;
  const int row0 = blockIdx.x * 128;

  {
    int r = t>>1, q = t&1;
    const uint4* src = (const uint4*)(Wt + r*128 + q*64);
    #pragma unroll
    for(int i=0;i<8;i++){
      uint4 v = src[i];
      int c = q*8 + i;
      *(uint4*)&Bs[r*128 + ((c ^ (r&15))<<3)] = v;
    }
  }
  {
    int r = t>>1, q = t&1;
    int gr = row0 + r;
    if(A_BF16){
      const uint4* src = (const uint4*)((const u16*)Xv + (size_t)gr*128 + q*64);
      uint4 z = make_uint4(0,0,0,0);
      #pragma unroll
      for(int i=0;i<8;i++){
        uint4 v = (gr<n)? src[i] : z;
        int c = q*8 + i;
        *(uint4*)&As[r*128 + ((c ^ (r&15))<<3)] = v;
      }
    }else{
      const float4* src = (const float4*)((const float*)Xv + (size_t)gr*128 + q*64);
      float4 z4 = make_float4(0,0,0,0);
      #pragma unroll
      for(int i=0;i<8;i++){
        float4 a = (gr<n)? src[2*i]   : z4;
        float4 b = (gr<n)? src[2*i+1] : z4;
        uint4 v = make_uint4(f2bf(a.x)|(f2bf(a.y)<<16), f2bf(a.z)|(f2bf(a.w)<<16),
                             f2bf(b.x)|(f2bf(b.y)<<16), f2bf(b.z)|(f2bf(b.w)<<16));
        int c = q*8 + i;
        *(uint4*)&As[r*128 + ((c ^ (r&15))<<3)] = v;
      }
    }
  }
  __syncthreads();

  const int w  = t>>6, l = t&63;
  const int lr = l & 15;
  const int kg = l >> 4;
  f32x4 acc[2][8];
  #pragma unroll
  for(int mi=0;mi<2;mi++)
    #pragma unroll
    for(int ni=0;ni<8;ni++) acc[mi][ni] = (f32x4){0.f,0.f,0.f,0.f};

  #pragma unroll
  for(int kt=0; kt<4; kt++){
    int c = kt*4 + kg;
    bf16x8 a0 = *(const bf16x8*)&As[(w*32 + lr)*128      + ((c ^ lr)<<3)];
    bf16x8 a1 = *(const bf16x8*)&As[(w*32 + 16 + lr)*128 + ((c ^ lr)<<3)];
    #pragma unroll
    for(int ni=0; ni<8; ni++){
      bf16x8 b = *(const bf16x8*)&Bs[(ni*16 + lr)*128 + ((c ^ lr)<<3)];
      acc[0][ni] = __builtin_amdgcn_mfma_f32_16x16x32_bf16(a0, b, acc[0][ni], 0,0,0);
      acc[1][ni] = __builtin_amdgcn_mfma_f32_16x16x32_bf16(a1, b, acc[1][ni], 0,0,0);
    }
  }

  #pragma unroll
  for(int mi=0;mi<2;mi++){
    #pragma unroll
    for(int r=0;r<4;r++){
      int grow = row0 + w*32 + mi*16 + kg*4 + r;
      if(grow < n){
        #pragma unroll
        for(int ni=0;ni<8;ni++){
          Y[(size_t)grow*128 + ni*16 + lr] = (u16)f2bf(acc[mi][ni][r]);
        }
      }
    }
  }
}

// ---------------- SpMM (D=128 bf16) + bias + relu -> bf16 ----------------
// quarter-wave per row: 16 lanes x uint4(8 bf16); 8-deep unroll main loop,
// one padded epilogue iteration (clamped idx, val=0).
__global__ __launch_bounds__(256) void k_spmm_relu(const int* __restrict__ row_ptr,
                                                   const int2* __restrict__ pairs,
                                                   const u16* __restrict__ y,
                                                   const float* __restrict__ bias,
                                                   u16* __restrict__ h, int n){
  int rowi = (int)((blockIdx.x*(size_t)blockDim.x + threadIdx.x) >> 4);
  int l    = threadIdx.x & 15;
  if(rowi >= n) return;
  int s = row_ptr[rowi], e = row_ptr[rowi+1];
  float acc[4][8];
  #pragma unroll
  for(int u=0;u<4;u++)
    #pragma unroll
    for(int k=0;k<8;k++) acc[u][k]=0.f;

  int i = s;
  for(; i+8 <= e; i += 8){
    uint4 w[8]; float v[8];
    #pragma unroll
    for(int u=0;u<8;u++){
      int2 p = pairs[i+u];
      v[u] = __int_as_float(p.y);
      w[u] = ((const uint4*)(y + (size_t)p.x*128))[l];
    }
    #pragma unroll
    for(int u=0;u<8;u++){
      float* a = acc[u&3];
      a[0]=fmaf(v[u], bf2f(w[u].x&0xffff), a[0]); a[1]=fmaf(v[u], bf2f(w[u].x>>16), a[1]);
      a[2]=fmaf(v[u], bf2f(w[u].y&0xffff), a[2]); a[3]=fmaf(v[u], bf2f(w[u].y>>16), a[3]);
      a[4]=fmaf(v[u], bf2f(w[u].z&0xffff), a[4]); a[5]=fmaf(v[u], bf2f(w[u].z>>16), a[5]);
      a[6]=fmaf(v[u], bf2f(w[u].w&0xffff), a[6]); a[7]=fmaf(v[u], bf2f(w[u].w>>16), a[7]);
    }
  }
  if(i < e){           // single padded iteration
    uint4 w[8]; float v[8];
    #pragma unroll
    for(int u=0;u<8;u++){
      int  q  = i + u;
      bool ok = q < e;
      int2 p  = pairs[ok ? q : e-1];
      v[u] = ok ? __int_as_float(p.y) : 0.f;
      w[u] = ((const uint4*)(y + (size_t)p.x*128))[l];
    }
    #pragma unroll
    for(int u=0;u<8;u++){
      float* a = acc[u&3];
      a[0]=fmaf(v[u], bf2f(w[u].x&0xffff), a[0]); a[1]=fmaf(v[u], bf2f(w[u].x>>16), a[1]);
      a[2]=fmaf(v[u], bf2f(w[u].y&0xffff), a[2]); a[3]=fmaf(v[u], bf2f(w[u].y>>16), a[3]);
      a[4]=fmaf(v[u], bf2f(w[u].z&0xffff), a[4]); a[5]=fmaf(v[u], bf2f(w[u].z>>16), a[5]);
      a[6]=fmaf(v[u], bf2f(w[u].w&0xffff), a[6]); a[7]=fmaf(v[u], bf2f(w[u].w>>16), a[7]);
    }
  }

  const float4* bp = (const float4*)(bias + l*8);
  float4 b0 = bp[0], b1 = bp[1];
  float f[8];
  #pragma unroll
  for(int k=0;k<8;k++) f[k] = (acc[0][k]+acc[1][k]) + (acc[2][k]+acc[3][k]);
  f[0]=fmaxf(f[0]+b0.x,0.f); f[1]=fmaxf(f[1]+b0.y,0.f);
  f[2]=fmaxf(f[2]+b0.z,0.f); f[3]=fmaxf(f[3]+b0.w,0.f);
  f[4]=fmaxf(f[4]+b1.x,0.f); f[5]=fmaxf(f[5]+b1.y,0.f);
  f[6]=fmaxf(f[6]+b1.z,0.f); f[7]=fmaxf(f[7]+b1.w,0.f);
  uint4 o = make_uint4(f2bf(f[0])|(f2bf(f[1])<<16), f2bf(f[2])|(f2bf(f[3])<<16),
                       f2bf(f[4])|(f2bf(f[5])<<16), f2bf(f[6])|(f2bf(f[7])<<16));
  *(uint4*)(h + (size_t)rowi*128 + l*8) = o;
}

// ---------------- SpMM(bf16) + bias + relu + head dot, fused -> z fp32 ----------------
__global__ __launch_bounds__(256) void k_spmm_head(const int* __restrict__ row_ptr,
                                                   const int2* __restrict__ pairs,
                                                   const u16* __restrict__ y,
                                                   const float* __restrict__ bias,
                                                   const float* __restrict__ Wout,
                                                   float* __restrict__ z, int n){
  int rowi = (int)((blockIdx.x*(size_t)blockDim.x + threadIdx.x) >> 4);
  int l    = threadIdx.x & 15;
  if(rowi >= n) return;
  int s = row_ptr[rowi], e = row_ptr[rowi+1];
  float acc[4][8];
  #pragma unroll
  for(int u=0;u<4;u++)
    #pragma unroll
    for(int k=0;k<8;k++) acc[u][k]=0.f;

  int i = s;
  for(; i+8 <= e; i += 8){
    uint4 w[8]; float v[8];
    #pragma unroll
    for(int u=0;u<8;u++){
      int2 p = pairs[i+u];
      v[u] = __int_as_float(p.y);
      w[u] = ((const uint4*)(y + (size_t)p.x*128))[l];
    }
    #pragma unroll
    for(int u=0;u<8;u++){
      float* a = acc[u&3];
      a[0]=fmaf(v[u], bf2f(w[u].x&0xffff), a[0]); a[1]=fmaf(v[u], bf2f(w[u].x>>16), a[1]);
      a[2]=fmaf(v[u], bf2f(w[u].y&0xffff), a[2]); a[3]=fmaf(v[u], bf2f(w[u].y>>16), a[3]);
      a[4]=fmaf(v[u], bf2f(w[u].z&0xffff), a[4]); a[5]=fmaf(v[u], bf2f(w[u].z>>16), a[5]);
      a[6]=fmaf(v[u], bf2f(w[u].w&0xffff), a[6]); a[7]=fmaf(v[u], bf2f(w[u].w>>16), a[7]);
    }
  }
  if(i < e){
    uint4 w[8]; float v[8];
    #pragma unroll
    for(int u=0;u<8;u++){
      int  q  = i + u;
      bool ok = q < e;
      int2 p  = pairs[ok ? q : e-1];
      v[u] = ok ? __int_as_float(p.y) : 0.f;
      w[u] = ((const uint4*)(y + (size_t)p.x*128))[l];
    }
    #pragma unroll
    for(int u=0;u<8;u++){
      float* a = acc[u&3];
      a[0]=fmaf(v[u], bf2f(w[u].x&0xffff), a[0]); a[1]=fmaf(v[u], bf2f(w[u].x>>16), a[1]);
      a[2]=fmaf(v[u], bf2f(w[u].y&0xffff), a[2]); a[3]=fmaf(v[u], bf2f(w[u].y>>16), a[3]);
      a[4]=fmaf(v[u], bf2f(w[u].z&0xffff), a[4]); a[5]=fmaf(v[u], bf2f(w[u].z>>16), a[5]);
      a[6]=fmaf(v[u], bf2f(w[u].w&0xffff), a[6]); a[7]=fmaf(v[u], bf2f(w[u].w>>16), a[7]);
    }
  }

  const float4* bp = (const float4*)(bias + l*8);
  const float4* wp = (const float4*)(Wout + l*8);
  float4 b0 = bp[0], b1 = bp[1];
  float4 w0 = wp[0], w1 = wp[1];
  float f[8];
  #pragma unroll
  for(int k=0;k<8;k++) f[k] = (acc[0][k]+acc[1][k]) + (acc[2][k]+acc[3][k]);
  float part = 0.f;
  part += fmaxf(f[0]+b0.x,0.f)*w0.x + fmaxf(f[1]+b0.y,0.f)*w0.y;
  part += fmaxf(f[2]+b0.z,0.f)*w0.z + fmaxf(f[3]+b0.w,0.f)*w0.w;
  part += fmaxf(f[4]+b1.x,0.f)*w1.x + fmaxf(f[5]+b1.y,0.f)*w1.y;
  part += fmaxf(f[6]+b1.z,0.f)*w1.z + fmaxf(f[7]+b1.w,0.f)*w1.w;
  #pragma unroll
  for(int off=1; off<16; off<<=1) part += __shfl_xor(part, off);
  if(l==0) z[rowi] = part;
}

// ---------------- final: out[r] = softplus(sum val*z[col] + bout) ----------------
__global__ void k_spmm1_softplus(const int* __restrict__ row_ptr,
                                 const int2* __restrict__ pairs,
                                 const float* __restrict__ z,
                                 const float* __restrict__ bout,
                                 float* __restrict__ out, int n){
  int r = blockIdx.x*256 + threadIdx.x;
  if(r >= n) return;
  int s = row_ptr[r], e = row_ptr[r+1];
  float a0=0.f, a1=0.f, a2=0.f, a3=0.f;
  int i = s;
  for(; i+4 <= e; i += 4){
    int2 p0 = pairs[i],   p1 = pairs[i+1], p2 = pairs[i+2], p3 = pairs[i+3];
    a0 = fmaf(__int_as_float(p0.y), z[p0.x], a0);
    a1 = fmaf(__int_as_float(p1.y), z[p1.x], a1);
    a2 = fmaf(__int_as_float(p2.y), z[p2.x], a2);
    a3 = fmaf(__int_as_float(p3.y), z[p3.x], a3);
  }
  for(; i < e; i++){
    int2 p = pairs[i];
    a0 = fmaf(__int_as_float(p.y), z[p.x], a0);
  }
  float x = (a0+a1)+(a2+a3) + bout[0];
  out[r] = fmaxf(x, 0.f) + log1pf(expf(-fabsf(x)));
}

extern "C" void kernel_launch(void* const* d_in, const int* in_sizes, int n_in,
                              void* d_out, int out_size, void* d_ws, size_t ws_size,
                              hipStream_t stream){
  const float* x    = (const float*)d_in[0];
  const int*   erow = (const int*)d_in[1];
  const int*   ecol = (const int*)d_in[2];
  const float* eval = (const float*)d_in[3];
  const float* W1   = (const float*)d_in[4];
  const float* b1   = (const float*)d_in[5];
  const float* W2   = (const float*)d_in[6];
  const float* b2   = (const float*)d_in[7];
  const float* Wout = (const float*)d_in[8];
  const float* bout = (const float*)d_in[9];
  float* out = (float*)d_out;

  const int N = in_sizes[0] / 128;   // 100000
  const int E = in_sizes[1];         // 1600000

  char* p = (char*)d_ws;
  auto alloc = [&](size_t bytes)->char*{
    char* r = p; p += (bytes + 255) & ~(size_t)255; return r;
  };
  int*   cnt     = (int*)  alloc((size_t)N*4);
  int*   row_ptr = (int*)  alloc((size_t)(N+1)*4);
  int*   offs    = (int*)  alloc((size_t)N*4);
  int*   scanned = (int*)  alloc((size_t)N*4);
  int*   sums    = (int*)  alloc(4096);
  int2*  pairs   = (int2*) alloc((size_t)E*8);
  u16*   ybuf    = (u16*)  alloc((size_t)N*128*2);
  u16*   hbuf    = (u16*)  alloc((size_t)N*128*2);
  float* z       = (float*)alloc((size_t)N*4);
  u16*   Wt1     = (u16*)  alloc(128*128*2);
  u16*   Wt2     = (u16*)  alloc(128*128*2);

  // CSR build
  hipMemsetAsync(cnt, 0, (size_t)N*4, stream);
  k_hist<<<(E+255)/256, 256, 0, stream>>>(erow, cnt, E);
  int ntiles = (N+1023)/1024;
  k_scan1<<<ntiles, 1024, 0, stream>>>(cnt, scanned, sums, N);
  k_scan2<<<1, 64, 0, stream>>>(sums, ntiles);
  k_scan3<<<(N+1+255)/256, 256, 0, stream>>>(scanned, sums, row_ptr, offs, N, E);
  k_scatter<<<1024, 256, 0, stream>>>(erow, ecol, eval, offs, pairs, E, N);

  // W pre-transpose/convert
  k_cvtW<<<64, 256, 0, stream>>>(W1, Wt1);
  k_cvtW<<<64, 256, 0, stream>>>(W2, Wt2);

  // layer 1: y = x@W1 (bf16 MFMA) ; h = relu(A y + b1) (bf16)
  k_gemm<false><<<(N+127)/128, 256, 0, stream>>>(x, Wt1, ybuf, N);
  k_spmm_relu<<<(N+15)/16, 256, 0, stream>>>(row_ptr, pairs, ybuf, b1, hbuf, N);
  // layer 2: y = h@W2 (bf16 MFMA) ; z = relu(A y + b2) . Wout
  k_gemm<true><<<(N+127)/128, 256, 0, stream>>>(hbuf, Wt2, ybuf, N);
  k_spmm_head<<<(N+15)/16, 256, 0, stream>>>(row_ptr, pairs, ybuf, b2, Wout, z, N);
  // out = softplus(A z + bout)
  k_spmm1_softplus<<<(N+255)/256, 256, 0, stream>>>(row_ptr, pairs, z, bout, out, N);
}